// Round 1
// baseline (128.574 us; speedup 1.0000x reference)
//
#include <hip/hip_runtime.h>

// Problem constants
#define N_  32
#define C_  32
#define H_  56
#define W_  56
#define O_  32
#define HP_ 58   // padded
#define WP_ 58
#define HW_ (H_*W_)          // 3136
#define CHW_ (C_*H_*W_)      // 100352
#define KK_ 9
#define CKK_ (C_*KK_)        // 288

// xT layout: [C][HP][WP][N]  (zero padded border), float
// size = 32*58*58*32 = 3,444,736 floats = 13,778,944 bytes
#define XT_FLOATS ((size_t)C_*HP_*WP_*N_)

// -------- transpose + pad:  x[N][C][H][W] -> xT[C][HP][WP][N] --------
__global__ __launch_bounds__(256) void xpose_kernel(const float* __restrict__ x,
                                                    float* __restrict__ xT) {
    const int c = blockIdx.x;   // 0..31
    const int y = blockIdx.y;   // 0..57 (padded row)
    __shared__ float sbuf[32 * 57];   // [n][col], row stride 57 (odd -> conflict-free)
    const int tid = threadIdx.x;
    const bool interior = (y >= 1) && (y <= H_);
    if (interior) {
        for (int idx = tid; idx < N_ * W_; idx += 256) {
            int n = idx / W_;
            int col = idx - n * W_;
            sbuf[n * 57 + col] = x[((size_t)(n * C_ + c) * H_ + (y - 1)) * W_ + col];
        }
    }
    __syncthreads();
    float* dst = xT + ((size_t)(c * HP_ + y)) * WP_ * N_;
    for (int idx = tid; idx < WP_ * N_; idx += 256) {
        int xx = idx >> 5;        // 0..57
        int n  = idx & 31;
        float v = 0.f;
        if (interior && xx >= 1 && xx <= W_) v = sbuf[n * 57 + (xx - 1)];
        dst[idx] = v;
    }
}

// -------- main: one wave per (o, h, w-tile of 8); thread = (w, 4 n's) --------
__global__ __launch_bounds__(64) void lc2d_main(const float* __restrict__ wgt,
                                                const float* __restrict__ xT,
                                                const float* __restrict__ bias,
                                                float* __restrict__ out) {
    const int wt = blockIdx.x;      // 0..6
    const int h  = blockIdx.y;      // 0..55
    const int o  = blockIdx.z;      // 0..31
    const int w0 = wt * 8;

    __shared__ float wbuf[8 * 292];  // rows padded 288->292 (bank offset 4/row)

    const int lane = threadIdx.x;   // 0..63
    const int w = lane >> 3;        // 0..7  (w0+w)
    const int g = lane & 7;         // 0..7  -> n = 4g .. 4g+3

    // stage 8*288 contiguous weight floats (coalesced float4)
    {
        const float4* src = (const float4*)(wgt + ((size_t)((o * H_ + h) * W_ + w0)) * CKK_);
        for (int t = lane; t < 576; t += 64) {
            int row = t / 72;            // w'
            int col = t - row * 72;
            ((float4*)wbuf)[row * 73 + col] = src[t];
        }
    }
    __syncthreads();

    float4 acc = make_float4(0.f, 0.f, 0.f, 0.f);
    const float* wrow = wbuf + w * 292;
    const float4* xp = (const float4*)xT;

    #pragma unroll 2
    for (int c = 0; c < C_; ++c) {
        const float* wc = wrow + c * KK_;
        // float4 index of xT[c][h+i][w0+w+j][4g]
        int base = ((c * HP_ + h) * WP_ + (w0 + w)) * 8 + g;
        #pragma unroll
        for (int i = 0; i < 3; ++i) {
            const float4* row = xp + base + i * (WP_ * 8);
            float wv0 = wc[i * 3 + 0];
            float wv1 = wc[i * 3 + 1];
            float wv2 = wc[i * 3 + 2];
            float4 a = row[0];
            float4 b = row[8];
            float4 d = row[16];
            acc.x = fmaf(wv0, a.x, acc.x);
            acc.y = fmaf(wv0, a.y, acc.y);
            acc.z = fmaf(wv0, a.z, acc.z);
            acc.w = fmaf(wv0, a.w, acc.w);
            acc.x = fmaf(wv1, b.x, acc.x);
            acc.y = fmaf(wv1, b.y, acc.y);
            acc.z = fmaf(wv1, b.z, acc.z);
            acc.w = fmaf(wv1, b.w, acc.w);
            acc.x = fmaf(wv2, d.x, acc.x);
            acc.y = fmaf(wv2, d.y, acc.y);
            acc.z = fmaf(wv2, d.z, acc.z);
            acc.w = fmaf(wv2, d.w, acc.w);
        }
    }

    const float bv = bias[(o * H_ + h) * W_ + w0 + w];
    acc.x += bv; acc.y += bv; acc.z += bv; acc.w += bv;

    // out[n][o][h][w]; n = 4g..4g+3
    size_t obase = (size_t)(4 * g) * CHW_ + (size_t)o * HW_ + h * W_ + (w0 + w);
    out[obase + 0 * (size_t)CHW_] = acc.x;
    out[obase + 1 * (size_t)CHW_] = acc.y;
    out[obase + 2 * (size_t)CHW_] = acc.z;
    out[obase + 3 * (size_t)CHW_] = acc.w;
}

// -------- fallback (if workspace too small): thread per output, bounds-checked --------
__global__ __launch_bounds__(256) void lc2d_naive(const float* __restrict__ x,
                                                  const float* __restrict__ wgt,
                                                  const float* __restrict__ bias,
                                                  float* __restrict__ out) {
    int idx = blockIdx.x * 256 + threadIdx.x;
    const int total = N_ * O_ * H_ * W_;
    if (idx >= total) return;
    int w = idx % W_;
    int h = (idx / W_) % H_;
    int o = (idx / HW_) % O_;
    int n = idx / CHW_;
    const float* wp = wgt + ((size_t)((o * H_ + h) * W_ + w)) * CKK_;
    float s = 0.f;
    for (int c = 0; c < C_; ++c) {
        for (int i = 0; i < 3; ++i) {
            int yy = h + i - 1;
            if (yy < 0 || yy >= H_) continue;
            for (int j = 0; j < 3; ++j) {
                int xx = w + j - 1;
                if (xx < 0 || xx >= W_) continue;
                s = fmaf(wp[c * KK_ + i * 3 + j],
                         x[((size_t)(n * C_ + c) * H_ + yy) * W_ + xx], s);
            }
        }
    }
    out[idx] = s + bias[idx % CHW_];
}

extern "C" void kernel_launch(void* const* d_in, const int* in_sizes, int n_in,
                              void* d_out, int out_size, void* d_ws, size_t ws_size,
                              hipStream_t stream) {
    const float* x    = (const float*)d_in[0];
    const float* wgt  = (const float*)d_in[1];
    const float* bias = (const float*)d_in[2];
    float* out = (float*)d_out;

    const size_t need = XT_FLOATS * sizeof(float);
    if (ws_size >= need) {
        float* xT = (float*)d_ws;
        hipLaunchKernelGGL(xpose_kernel, dim3(C_, HP_), dim3(256), 0, stream, x, xT);
        hipLaunchKernelGGL(lc2d_main, dim3(7, H_, O_), dim3(64), 0, stream, wgt, xT, bias, out);
    } else {
        int total = N_ * O_ * H_ * W_;
        hipLaunchKernelGGL(lc2d_naive, dim3((total + 255) / 256), dim3(256), 0, stream,
                           x, wgt, bias, out);
    }
}

// Round 2
// 45.367 us; speedup vs baseline: 2.8341x; 2.8341x over previous
//
#include <hip/hip_runtime.h>

// Problem constants
#define N_  32
#define C_  32
#define H_  56
#define W_  56
#define O_  32
#define HP_ 58   // padded
#define WP_ 58
#define HW_ (H_*W_)          // 3136
#define CHW_ (C_*H_*W_)      // 100352
#define KK_ 9
#define CKK_ (C_*KK_)        // 288

// xT layout: [C][HP][WP][N]  (zero padded border), float
#define XT_FLOATS ((size_t)C_*HP_*WP_*N_)

typedef __bf16 bf16x8 __attribute__((ext_vector_type(8)));
typedef float  f32x4  __attribute__((ext_vector_type(4)));

// -------- transpose + pad:  x[N][C][H][W] -> xT[C][HP][WP][N] --------
__global__ __launch_bounds__(256) void xpose_kernel(const float* __restrict__ x,
                                                    float* __restrict__ xT) {
    const int c = blockIdx.x;   // 0..31
    const int y = blockIdx.y;   // 0..57 (padded row)
    __shared__ float sbuf[32 * 57];   // [n][col], row stride 57
    const int tid = threadIdx.x;
    const bool interior = (y >= 1) && (y <= H_);
    if (interior) {
        for (int idx = tid; idx < N_ * W_; idx += 256) {
            int n = idx / W_;
            int col = idx - n * W_;
            sbuf[n * 57 + col] = x[((size_t)(n * C_ + c) * H_ + (y - 1)) * W_ + col];
        }
    }
    __syncthreads();
    float* dst = xT + ((size_t)(c * HP_ + y)) * WP_ * N_;
    for (int idx = tid; idx < WP_ * N_; idx += 256) {
        int xx = idx >> 5;        // 0..57
        int n  = idx & 31;
        float v = 0.f;
        if (interior && xx >= 1 && xx <= W_) v = sbuf[n * 57 + (xx - 1)];
        dst[idx] = v;
    }
}

// -------- MFMA main: block = 4 waves = 4 adjacent w at one h; wave = one position GEMM
// Per position: C[n=32][o=32] = sum_k A[n][k] * Wt[o][k],  k = c*9 + i*3 + j  (K=288)
// A[n][k] = xT[c][h+i][w+j][n]   (padded coords),  Wt[o][k] = wgt[o][h][w][k] (contiguous per o)
__global__ __launch_bounds__(256) void lc2d_mfma(const float* __restrict__ wgt,
                                                 const float* __restrict__ xT,
                                                 const float* __restrict__ bias,
                                                 float* __restrict__ out) {
    __shared__ int offs[288];
    __shared__ __align__(16) float sbuf[32][33][4];   // [n][o pad33][w4]

    const int tid = threadIdx.x;
    // x-gather offset table (position-independent), in floats
    for (int k = tid; k < 288; k += 256) {
        int c = k / 9, ij = k - 9 * c;
        int i = ij / 3, j = ij - 3 * i;
        offs[k] = c * (HP_ * WP_ * N_) + i * (WP_ * N_) + j * N_;
    }
    __syncthreads();

    // bijective XCD-chunk swizzle: 784 blocks = 8 XCDs x 98 consecutive wg ids
    const int flat = blockIdx.x;
    const int wg = (flat & 7) * 98 + (flat >> 3);
    const int wt = wg % 14;          // w-tile (w-major => adjacent w-tiles same XCD)
    const int h  = wg / 14;          // 0..55
    const int wave = tid >> 6;       // 0..3
    const int lane = tid & 63;
    const int w = wt * 4 + wave;     // this wave's position
    const int q = lane >> 4;         // k-group 0..3
    const int r = lane & 15;         // o (B-frag) / n (A-frag) within tile

    // B (weight) fragment bases: lane reads 8 consecutive fp32 of row o
    const float* wb0 = wgt + ((size_t)(r * HW_ + h * W_ + w)) * CKK_ + 8 * q;   // o = r
    const float* wb1 = wb0 + (size_t)16 * HW_ * CKK_;                           // o = r+16
    // A base: n = r (and +16 floats => n = r+16)
    const float* ab = xT + (h * WP_ + w) * N_ + r;

    f32x4 acc00 = {0.f,0.f,0.f,0.f}, acc01 = {0.f,0.f,0.f,0.f};
    f32x4 acc10 = {0.f,0.f,0.f,0.f}, acc11 = {0.f,0.f,0.f,0.f};

    #pragma unroll 3
    for (int s = 0; s < 9; ++s) {
        const int4 ov0 = *(const int4*)&offs[32 * s + 8 * q];
        const int4 ov1 = *(const int4*)&offs[32 * s + 8 * q + 4];
        const float4 b0a = *(const float4*)(wb0 + 32 * s);
        const float4 b0b = *(const float4*)(wb0 + 32 * s + 4);
        const float4 b1a = *(const float4*)(wb1 + 32 * s);
        const float4 b1b = *(const float4*)(wb1 + 32 * s + 4);

        const int offv[8] = {ov0.x, ov0.y, ov0.z, ov0.w, ov1.x, ov1.y, ov1.z, ov1.w};
        float a0[8], a1[8];
        #pragma unroll
        for (int t = 0; t < 8; ++t) {
            const float* p = ab + offv[t];
            a0[t] = p[0];     // n = r
            a1[t] = p[16];    // n = r+16  (offset:64 fold)
        }

        bf16x8 af0, af1, bf0, bf1;
        #pragma unroll
        for (int t = 0; t < 8; ++t) {
            af0[t] = (__bf16)a0[t];
            af1[t] = (__bf16)a1[t];
        }
        bf0[0] = (__bf16)b0a.x; bf0[1] = (__bf16)b0a.y; bf0[2] = (__bf16)b0a.z; bf0[3] = (__bf16)b0a.w;
        bf0[4] = (__bf16)b0b.x; bf0[5] = (__bf16)b0b.y; bf0[6] = (__bf16)b0b.z; bf0[7] = (__bf16)b0b.w;
        bf1[0] = (__bf16)b1a.x; bf1[1] = (__bf16)b1a.y; bf1[2] = (__bf16)b1a.z; bf1[3] = (__bf16)b1a.w;
        bf1[4] = (__bf16)b1b.x; bf1[5] = (__bf16)b1b.y; bf1[6] = (__bf16)b1b.z; bf1[7] = (__bf16)b1b.w;

        acc00 = __builtin_amdgcn_mfma_f32_16x16x32_bf16(af0, bf0, acc00, 0, 0, 0);
        acc01 = __builtin_amdgcn_mfma_f32_16x16x32_bf16(af0, bf1, acc01, 0, 0, 0);
        acc10 = __builtin_amdgcn_mfma_f32_16x16x32_bf16(af1, bf0, acc10, 0, 0, 0);
        acc11 = __builtin_amdgcn_mfma_f32_16x16x32_bf16(af1, bf1, acc11, 0, 0, 0);
    }

    // stage C into LDS: n = mt*16 + q*4 + reg, o = ot*16 + r (verified C/D layout)
    #pragma unroll
    for (int mt = 0; mt < 2; ++mt) {
        #pragma unroll
        for (int ot = 0; ot < 2; ++ot) {
            f32x4 a = (mt == 0) ? (ot == 0 ? acc00 : acc01)
                                : (ot == 0 ? acc10 : acc11);
            const int o = ot * 16 + r;
            #pragma unroll
            for (int reg = 0; reg < 4; ++reg) {
                const int n = mt * 16 + q * 4 + reg;
                sbuf[n][o][wave] = a[reg];
            }
        }
    }
    __syncthreads();

    // coalesced-ish store: float4 over w0..w0+3 per (n,o), + bias
    const int w0 = wt * 4;
    #pragma unroll
    for (int rr = 0; rr < 4; ++rr) {
        const int fl = rr * 256 + tid;
        const int n = fl >> 5;
        const int o = fl & 31;
        float4 v = *(const float4*)&sbuf[n][o][0];
        const float4 bv = *(const float4*)(bias + o * HW_ + h * W_ + w0);
        v.x += bv.x; v.y += bv.y; v.z += bv.z; v.w += bv.w;
        *(float4*)(out + (size_t)n * CHW_ + o * HW_ + h * W_ + w0) = v;
    }
}

// -------- fallback (if workspace too small): thread per output, bounds-checked --------
__global__ __launch_bounds__(256) void lc2d_naive(const float* __restrict__ x,
                                                  const float* __restrict__ wgt,
                                                  const float* __restrict__ bias,
                                                  float* __restrict__ out) {
    int idx = blockIdx.x * 256 + threadIdx.x;
    const int total = N_ * O_ * H_ * W_;
    if (idx >= total) return;
    int w = idx % W_;
    int h = (idx / W_) % H_;
    int o = (idx / HW_) % O_;
    int n = idx / CHW_;
    const float* wp = wgt + ((size_t)((o * H_ + h) * W_ + w)) * CKK_;
    float s = 0.f;
    for (int c = 0; c < C_; ++c) {
        for (int i = 0; i < 3; ++i) {
            int yy = h + i - 1;
            if (yy < 0 || yy >= H_) continue;
            for (int j = 0; j < 3; ++j) {
                int xx = w + j - 1;
                if (xx < 0 || xx >= W_) continue;
                s = fmaf(wp[c * KK_ + i * 3 + j],
                         x[((size_t)(n * C_ + c) * H_ + yy) * W_ + xx], s);
            }
        }
    }
    out[idx] = s + bias[idx % CHW_];
}

extern "C" void kernel_launch(void* const* d_in, const int* in_sizes, int n_in,
                              void* d_out, int out_size, void* d_ws, size_t ws_size,
                              hipStream_t stream) {
    const float* x    = (const float*)d_in[0];
    const float* wgt  = (const float*)d_in[1];
    const float* bias = (const float*)d_in[2];
    float* out = (float*)d_out;

    const size_t need = XT_FLOATS * sizeof(float);
    if (ws_size >= need) {
        float* xT = (float*)d_ws;
        hipLaunchKernelGGL(xpose_kernel, dim3(C_, HP_), dim3(256), 0, stream, x, xT);
        hipLaunchKernelGGL(lc2d_mfma, dim3(784), dim3(256), 0, stream, wgt, xT, bias, out);
    } else {
        int total = N_ * O_ * H_ * W_;
        hipLaunchKernelGGL(lc2d_naive, dim3((total + 255) / 256), dim3(256), 0, stream,
                           x, wgt, bias, out);
    }
}

// Round 3
// 42.673 us; speedup vs baseline: 3.0130x; 1.0631x over previous
//
#include <hip/hip_runtime.h>

// Problem constants
#define N_  32
#define C_  32
#define H_  56
#define W_  56
#define O_  32
#define HP_ 58   // padded
#define WP_ 58
#define HW_ (H_*W_)          // 3136
#define CHW_ (C_*H_*W_)      // 100352
#define KK_ 9
#define CKK_ (C_*KK_)        // 288

// xT layout: [C][HP][WP][N] (zero padded border), bf16
#define XT_ELEMS ((size_t)C_*HP_*WP_*N_)

typedef __bf16 bf16x8 __attribute__((ext_vector_type(8)));
typedef float  f32x4  __attribute__((ext_vector_type(4)));

// -------- transpose + pad + bf16-convert:  x[N][C][H][W] -> xT[C][HP][WP][N] --------
__global__ __launch_bounds__(256) void xpose_kernel(const float* __restrict__ x,
                                                    __bf16* __restrict__ xT) {
    const int c = blockIdx.x;   // 0..31
    const int y = blockIdx.y;   // 0..57 (padded row)
    __shared__ float sbuf[32 * 57];   // [n][col], row stride 57
    const int tid = threadIdx.x;
    const bool interior = (y >= 1) && (y <= H_);
    if (interior) {
        for (int idx = tid; idx < N_ * W_; idx += 256) {
            int n = idx / W_;
            int col = idx - n * W_;
            sbuf[n * 57 + col] = x[((size_t)(n * C_ + c) * H_ + (y - 1)) * W_ + col];
        }
    }
    __syncthreads();
    __bf16* dst = xT + ((size_t)(c * HP_ + y)) * WP_ * N_;
    for (int idx = tid; idx < WP_ * N_; idx += 256) {
        int xx = idx >> 5;        // 0..57
        int n  = idx & 31;
        float v = 0.f;
        if (interior && xx >= 1 && xx <= W_) v = sbuf[n * 57 + (xx - 1)];
        dst[idx] = (__bf16)v;
    }
}

// -------- MFMA main --------
// Per position (h,w): C[n=32][o=32] = sum_k A[n][k] * Wt[o][k], k = c*9+i*3+j (K=288)
// Wave = (w, o-half): 16x16x32 MFMA, acc over both n-halves.
// Block = 4 waves = 2 adjacent w  x  2 o-halves. Grid = 28 w-tiles * 56 h = 1568.
__global__ __launch_bounds__(256) void lc2d_mfma(const float* __restrict__ wgt,
                                                 const __bf16* __restrict__ xT,
                                                 const float* __restrict__ bias,
                                                 float* __restrict__ out) {
    __shared__ int offs[288];
    __shared__ __align__(16) float sbuf[32][33][2];   // [n][o pad33][w2]

    const int tid = threadIdx.x;
    // x-gather offset table (position-independent), in elements
    for (int k = tid; k < 288; k += 256) {
        int c = k / 9, ij = k - 9 * c;
        int i = ij / 3, j = ij - 3 * i;
        offs[k] = c * (HP_ * WP_ * N_) + i * (WP_ * N_) + j * N_;
    }
    __syncthreads();

    // bijective XCD-chunk swizzle: 1568 blocks = 8 XCDs x 196 consecutive wg ids
    const int flat = blockIdx.x;
    const int wg = (flat & 7) * 196 + (flat >> 3);
    const int wt = wg % 28;          // w-tile of 2 (w-major => adjacent tiles same XCD)
    const int h  = wg / 28;          // 0..55
    const int wave = tid >> 6;       // 0..3
    const int lane = tid & 63;
    const int dw = wave & 1;         // which w of the pair
    const int oh = wave >> 1;        // which o-half
    const int w  = wt * 2 + dw;
    const int q = lane >> 4;         // k-group 0..3
    const int r = lane & 15;         // o (B-frag) / n (A-frag) within tile

    // B (weight) base: lane reads 8 consecutive fp32 of row o = oh*16 + r
    const float* wb = wgt + ((size_t)((oh * 16 + r) * HW_ + h * W_ + w)) * CKK_ + 8 * q;
    // A base: n = r (and +16 elements => n = r+16)
    const __bf16* ab = xT + (h * WP_ + w) * N_ + r;

    f32x4 acc0 = {0.f, 0.f, 0.f, 0.f};   // n 0..15
    f32x4 acc1 = {0.f, 0.f, 0.f, 0.f};   // n 16..31

    #pragma unroll 3
    for (int s = 0; s < 9; ++s) {
        const int4 ov0 = *(const int4*)&offs[32 * s + 8 * q];
        const int4 ov1 = *(const int4*)&offs[32 * s + 8 * q + 4];
        const float4 ba = *(const float4*)(wb + 32 * s);
        const float4 bb = *(const float4*)(wb + 32 * s + 4);

        const int offv[8] = {ov0.x, ov0.y, ov0.z, ov0.w, ov1.x, ov1.y, ov1.z, ov1.w};
        bf16x8 af0, af1, bfB;
        #pragma unroll
        for (int t = 0; t < 8; ++t) {
            const __bf16* p = ab + offv[t];
            af0[t] = p[0];     // n = r
            af1[t] = p[16];    // n = r+16
        }
        bfB[0] = (__bf16)ba.x; bfB[1] = (__bf16)ba.y; bfB[2] = (__bf16)ba.z; bfB[3] = (__bf16)ba.w;
        bfB[4] = (__bf16)bb.x; bfB[5] = (__bf16)bb.y; bfB[6] = (__bf16)bb.z; bfB[7] = (__bf16)bb.w;

        acc0 = __builtin_amdgcn_mfma_f32_16x16x32_bf16(af0, bfB, acc0, 0, 0, 0);
        acc1 = __builtin_amdgcn_mfma_f32_16x16x32_bf16(af1, bfB, acc1, 0, 0, 0);
    }

    // stage C into LDS: n = mt*16 + q*4 + reg, o = oh*16 + r (layout verified round 2)
    #pragma unroll
    for (int mt = 0; mt < 2; ++mt) {
        f32x4 a = mt == 0 ? acc0 : acc1;
        const int o = oh * 16 + r;
        #pragma unroll
        for (int reg = 0; reg < 4; ++reg) {
            const int n = mt * 16 + q * 4 + reg;
            sbuf[n][o][dw] = a[reg];
        }
    }
    __syncthreads();

    // store: float2 over {w0, w0+1} per (n,o), + bias
    const int w0 = wt * 2;
    #pragma unroll
    for (int rr = 0; rr < 4; ++rr) {
        const int fl = rr * 256 + tid;   // 0..1023 -> (n,o)
        const int n = fl >> 5;
        const int o = fl & 31;
        float2 v = *(const float2*)&sbuf[n][o][0];
        const float2 bv = *(const float2*)(bias + o * HW_ + h * W_ + w0);
        v.x += bv.x; v.y += bv.y;
        *(float2*)(out + (size_t)n * CHW_ + o * HW_ + h * W_ + w0) = v;
    }
}

// -------- fallback (if workspace too small): thread per output, bounds-checked --------
__global__ __launch_bounds__(256) void lc2d_naive(const float* __restrict__ x,
                                                  const float* __restrict__ wgt,
                                                  const float* __restrict__ bias,
                                                  float* __restrict__ out) {
    int idx = blockIdx.x * 256 + threadIdx.x;
    const int total = N_ * O_ * H_ * W_;
    if (idx >= total) return;
    int w = idx % W_;
    int h = (idx / W_) % H_;
    int o = (idx / HW_) % O_;
    int n = idx / CHW_;
    const float* wp = wgt + ((size_t)((o * H_ + h) * W_ + w)) * CKK_;
    float s = 0.f;
    for (int c = 0; c < C_; ++c) {
        for (int i = 0; i < 3; ++i) {
            int yy = h + i - 1;
            if (yy < 0 || yy >= H_) continue;
            for (int j = 0; j < 3; ++j) {
                int xx = w + j - 1;
                if (xx < 0 || xx >= W_) continue;
                s = fmaf(wp[c * KK_ + i * 3 + j],
                         x[((size_t)(n * C_ + c) * H_ + yy) * W_ + xx], s);
            }
        }
    }
    out[idx] = s + bias[idx % CHW_];
}

extern "C" void kernel_launch(void* const* d_in, const int* in_sizes, int n_in,
                              void* d_out, int out_size, void* d_ws, size_t ws_size,
                              hipStream_t stream) {
    const float* x    = (const float*)d_in[0];
    const float* wgt  = (const float*)d_in[1];
    const float* bias = (const float*)d_in[2];
    float* out = (float*)d_out;

    const size_t need = XT_ELEMS * sizeof(__bf16);
    if (ws_size >= need) {
        __bf16* xT = (__bf16*)d_ws;
        hipLaunchKernelGGL(xpose_kernel, dim3(C_, HP_), dim3(256), 0, stream, x, xT);
        hipLaunchKernelGGL(lc2d_mfma, dim3(1568), dim3(256), 0, stream, wgt, xT, bias, out);
    } else {
        int total = N_ * O_ * H_ * W_;
        hipLaunchKernelGGL(lc2d_naive, dim3((total + 255) / 256), dim3(256), 0, stream,
                           x, wgt, bias, out);
    }
}